// Round 1
// 333.072 us; speedup vs baseline: 1.0245x; 1.0245x over previous
//
#include <hip/hip_runtime.h>
#include <stdint.h>

// Problem constants (PureSAGEConv): N=50000, C_in=512, C_out=512, E=800000
#define CI 512
#define CO 512

typedef __attribute__((ext_vector_type(4))) float f32x4;
typedef __attribute__((ext_vector_type(8))) __bf16 bf16x8;

__device__ __forceinline__ unsigned short f2bf_bits(float f) {
  union { float f; unsigned int u; } v; v.f = f;
  unsigned int u = v.u;
  unsigned int lsb = (u >> 16) & 1u;
  u += 0x7fffu + lsb;                 // round-to-nearest-even
  return (unsigned short)(u >> 16);
}

// ---- f32 -> bf16 conversion (vectorized float4 -> ushort4) ----
__global__ void k_convert(const float* __restrict__ in,
                          unsigned short* __restrict__ out, int n4) {
  int i = blockIdx.x * 256 + threadIdx.x;
  if (i < n4) {
    float4 v = reinterpret_cast<const float4*>(in)[i];
    ushort4 o;
    o.x = f2bf_bits(v.x); o.y = f2bf_bits(v.y);
    o.z = f2bf_bits(v.z); o.w = f2bf_bits(v.w);
    reinterpret_cast<ushort4*>(out)[i] = o;
  }
}

// ---- degree histogram ----
__global__ void k_degree(const int* __restrict__ dst, int* __restrict__ cnt, int E) {
  int e = blockIdx.x * 256 + threadIdx.x;
  if (e < E) atomicAdd(&cnt[dst[e]], 1);
}

// ---- hierarchical scan: cnt[n] -> rowptr[n+1] (exclusive, rowptr[0]=0) ----
__global__ void k_bsum(const int* __restrict__ cnt, int* __restrict__ bsum, int n) {
  int t = threadIdx.x;
  int i = blockIdx.x * 256 + t;
  int v = (i < n) ? cnt[i] : 0;
  #pragma unroll
  for (int off = 32; off; off >>= 1) v += __shfl_down(v, off, 64);
  __shared__ int ws[4];
  if ((t & 63) == 0) ws[t >> 6] = v;
  __syncthreads();
  if (t == 0) bsum[blockIdx.x] = ws[0] + ws[1] + ws[2] + ws[3];
}

__global__ void k_scanb(const int* __restrict__ bsum, int* __restrict__ boff, int nb) {
  // nb <= 256
  int t = threadIdx.x, lane = t & 63, w = t >> 6;
  int v = (t < nb) ? bsum[t] : 0;
  int s = v;
  #pragma unroll
  for (int off = 1; off < 64; off <<= 1) {
    int u = __shfl_up(s, off, 64);
    if (lane >= off) s += u;
  }
  __shared__ int ws[4];
  if (lane == 63) ws[w] = s;
  __syncthreads();
  int add = 0;
  for (int j = 0; j < w; ++j) add += ws[j];
  if (t < nb) boff[t] = s + add - v;   // exclusive block offset
}

__global__ void k_scanf(const int* __restrict__ cnt, const int* __restrict__ boff,
                        int* __restrict__ rowptr, int n) {
  int t = threadIdx.x, lane = t & 63, w = t >> 6;
  int i = blockIdx.x * 256 + t;
  int v = (i < n) ? cnt[i] : 0;
  int s = v;
  #pragma unroll
  for (int off = 1; off < 64; off <<= 1) {
    int u = __shfl_up(s, off, 64);
    if (lane >= off) s += u;
  }
  __shared__ int ws[4];
  if (lane == 63) ws[w] = s;
  __syncthreads();
  int add = boff[blockIdx.x];
  for (int j = 0; j < w; ++j) add += ws[j];
  if (i < n) rowptr[i + 1] = s + add;
  if (i == 0) rowptr[0] = 0;
}

// ---- counting-sort fill of CSR neighbor lists ----
__global__ void k_fill(const int* __restrict__ src, const int* __restrict__ dst,
                       const int* __restrict__ rowptr, int* __restrict__ cursor,
                       int* __restrict__ csr, int E) {
  int e = blockIdx.x * 256 + threadIdx.x;
  if (e < E) {
    int d = dst[e];
    int pos = atomicAdd(&cursor[d], 1);
    csr[rowptr[d] + pos] = src[e];
  }
}

// ---- per-node neighbor mean: ONE WAVE per node, 16B/lane gathers ----
__device__ __forceinline__ void acc8(float* s, uint4 r) {
  const unsigned int u[4] = {r.x, r.y, r.z, r.w};
  #pragma unroll
  for (int k = 0; k < 4; ++k) {
    union { unsigned int u; float f; } lo, hi;
    lo.u = u[k] << 16;
    hi.u = u[k] & 0xffff0000u;
    s[2 * k]     += lo.f;
    s[2 * k + 1] += hi.f;
  }
}

__global__ __launch_bounds__(256) void k_aggregate(
    const unsigned short* __restrict__ xb,
    const int* __restrict__ rowptr,
    const int* __restrict__ csr,
    unsigned short* __restrict__ meanb, int Nn) {
  const int wid = blockIdx.x * 4 + (threadIdx.x >> 6);   // node id
  const int lane = threadIdx.x & 63;
  if (wid >= Nn) return;
  const int beg = rowptr[wid];
  const int deg = rowptr[wid + 1] - beg;
  float s[8] = {};
  const size_t laneoff = (size_t)lane * 8;

  for (int base = 0; base < deg; base += 64) {
    const int rem = deg - base;
    const int cnt = rem < 64 ? rem : 64;
    int nidx = 0;
    if (lane < cnt) nidx = csr[beg + base + lane];   // 64 indices per load
    int j = 0;
    for (; j + 4 <= cnt; j += 4) {                   // 4 gathers in flight
      int u0 = __shfl(nidx, j, 64);
      int u1 = __shfl(nidx, j + 1, 64);
      int u2 = __shfl(nidx, j + 2, 64);
      int u3 = __shfl(nidx, j + 3, 64);
      uint4 r0 = *reinterpret_cast<const uint4*>(xb + (size_t)u0 * CI + laneoff);
      uint4 r1 = *reinterpret_cast<const uint4*>(xb + (size_t)u1 * CI + laneoff);
      uint4 r2 = *reinterpret_cast<const uint4*>(xb + (size_t)u2 * CI + laneoff);
      uint4 r3 = *reinterpret_cast<const uint4*>(xb + (size_t)u3 * CI + laneoff);
      acc8(s, r0); acc8(s, r1); acc8(s, r2); acc8(s, r3);
    }
    for (; j < cnt; ++j) {
      int u = __shfl(nidx, j, 64);
      uint4 r = *reinterpret_cast<const uint4*>(xb + (size_t)u * CI + laneoff);
      acc8(s, r);
    }
  }

  const float inv = 1.f / fmaxf((float)deg, 1.f);
  unsigned short ob[8];
  #pragma unroll
  for (int k = 0; k < 8; ++k) ob[k] = f2bf_bits(s[k] * inv);
  uint4 w;
  w.x = (unsigned int)ob[0] | ((unsigned int)ob[1] << 16);
  w.y = (unsigned int)ob[2] | ((unsigned int)ob[3] << 16);
  w.z = (unsigned int)ob[4] | ((unsigned int)ob[5] << 16);
  w.w = (unsigned int)ob[6] | ((unsigned int)ob[7] << 16);
  *reinterpret_cast<uint4*>(meanb + (size_t)wid * CI + laneoff) = w;
}

// ---- bf16 MFMA GEMM: out[M][512] = [xb|meanb][M][1024] . Wb[512][1024]^T + b ----
#define BM 128
#define BN 128
#define BK 32

__global__ __launch_bounds__(256) void k_gemm(
    const unsigned short* __restrict__ xb,
    const unsigned short* __restrict__ meanb,
    const unsigned short* __restrict__ Wb,
    const float* __restrict__ bias,
    float* __restrict__ out, int M) {
  __shared__ unsigned short lds_a[BM * BK];
  __shared__ unsigned short lds_b[BN * BK];
  const int tid = threadIdx.x;
  const int ntn = CO / BN;                       // 4

  // Bijective XCD-aware swizzle (m204 formula; nwg=1564 is NOT %8==0).
  // Consecutive wg within one XCD chunk share the same A-stripe (tn fastest),
  // so the 4 n-tiles of an m-stripe hit the same XCD L2 instead of 4 XCDs.
  const int nwg = gridDim.x;
  const int NX = 8;
  const int q = nwg / NX, r = nwg % NX;
  const int xcd = blockIdx.x % NX, lid = blockIdx.x / NX;
  const int wg = (xcd < r ? xcd * (q + 1) : r * (q + 1) + (xcd - r) * q) + lid;

  const int tm = wg / ntn, tn = wg % ntn;
  const int m0 = tm * BM, n0 = tn * BN;
  const int lane = tid & 63, w = tid >> 6;
  const int wm = w >> 1, wn = w & 1;
  const int lrow = lane & 15, lk = (lane >> 4) * 8;
  const int r0 = tid >> 2, c8 = (tid & 3) << 3;  // staging: 4 threads/row

  f32x4 acc[4][4] = {};

  for (int k0 = 0; k0 < 2 * CI; k0 += BK) {
    const unsigned short* Asrc = (k0 < CI) ? xb : meanb;
    const int ksub = k0 & (CI - 1);
    __syncthreads();
    {
      int gr0 = m0 + r0;      if (gr0 >= M) gr0 = M - 1;
      int gr1 = m0 + r0 + 64; if (gr1 >= M) gr1 = M - 1;
      __builtin_amdgcn_global_load_lds(
        (const __attribute__((address_space(1))) unsigned int*)(uintptr_t)(Asrc + (size_t)gr0 * CI + ksub + c8),
        (__attribute__((address_space(3))) unsigned int*)(uintptr_t)(&lds_a[(size_t)tid * 8]), 16, 0, 0);
      __builtin_amdgcn_global_load_lds(
        (const __attribute__((address_space(1))) unsigned int*)(uintptr_t)(Asrc + (size_t)gr1 * CI + ksub + c8),
        (__attribute__((address_space(3))) unsigned int*)(uintptr_t)(&lds_a[(size_t)(256 + tid) * 8]), 16, 0, 0);
      __builtin_amdgcn_global_load_lds(
        (const __attribute__((address_space(1))) unsigned int*)(uintptr_t)(Wb + (size_t)(n0 + r0) * (2 * CI) + k0 + c8),
        (__attribute__((address_space(3))) unsigned int*)(uintptr_t)(&lds_b[(size_t)tid * 8]), 16, 0, 0);
      __builtin_amdgcn_global_load_lds(
        (const __attribute__((address_space(1))) unsigned int*)(uintptr_t)(Wb + (size_t)(n0 + r0 + 64) * (2 * CI) + k0 + c8),
        (__attribute__((address_space(3))) unsigned int*)(uintptr_t)(&lds_b[(size_t)(256 + tid) * 8]), 16, 0, 0);
    }
    __syncthreads();
    bf16x8 af[4], bfr[4];
    #pragma unroll
    for (int mi = 0; mi < 4; ++mi)
      af[mi] = *reinterpret_cast<const bf16x8*>(&lds_a[(wm * 64 + mi * 16 + lrow) * BK + lk]);
    #pragma unroll
    for (int ni = 0; ni < 4; ++ni)
      bfr[ni] = *reinterpret_cast<const bf16x8*>(&lds_b[(wn * 64 + ni * 16 + lrow) * BK + lk]);
    #pragma unroll
    for (int mi = 0; mi < 4; ++mi)
      #pragma unroll
      for (int ni = 0; ni < 4; ++ni)
        acc[mi][ni] = __builtin_amdgcn_mfma_f32_16x16x32_bf16(af[mi], bfr[ni], acc[mi][ni], 0, 0, 0);
  }

  #pragma unroll
  for (int mi = 0; mi < 4; ++mi) {
    #pragma unroll
    for (int ni = 0; ni < 4; ++ni) {
      const int col = n0 + wn * 64 + ni * 16 + lrow;
      const float bb = bias[col];
      #pragma unroll
      for (int j = 0; j < 4; ++j) {
        int row = m0 + wm * 64 + mi * 16 + (lane >> 4) * 4 + j;
        if (row < M) out[(size_t)row * CO + col] = acc[mi][ni][j] + bb;
      }
    }
  }
}

extern "C" void kernel_launch(void* const* d_in, const int* in_sizes, int n_in,
                              void* d_out, int out_size, void* d_ws, size_t ws_size,
                              hipStream_t stream) {
  (void)n_in; (void)out_size; (void)ws_size;
  const float* x    = (const float*)d_in[0];
  const int*   ei   = (const int*)d_in[1];
  const float* W    = (const float*)d_in[2];
  const float* bias = (const float*)d_in[3];
  float* out = (float*)d_out;

  const int Nn = in_sizes[0] / CI;     // 50000
  const int E  = in_sizes[1] / 2;      // 800000
  const int* src = ei;
  const int* dst = ei + E;

  const int nblk = (Nn + 255) / 256;   // 196 scan blocks

  // workspace layout (~107 MB):
  int* cnt    = (int*)d_ws;            // [Nn]
  int* cursor = cnt + Nn;              // [Nn]
  int* rowptr = cursor + Nn;           // [Nn+1]
  int* bsum   = rowptr + (Nn + 1);     // [nblk]
  int* boff   = bsum + nblk;           // [nblk]
  int* csr    = boff + nblk;           // [E]
  uintptr_t p = (uintptr_t)(csr + E);
  p = (p + 255) & ~(uintptr_t)255;
  unsigned short* xb    = (unsigned short*)p;           // [Nn*CI] bf16
  unsigned short* meanb = xb + (size_t)Nn * CI;         // [Nn*CI] bf16
  unsigned short* Wb    = meanb + (size_t)Nn * CI;      // [CO*2CI] bf16

  hipMemsetAsync(cnt, 0, (size_t)2 * Nn * sizeof(int), stream);  // cnt + cursor

  const int nx4 = (Nn * CI) / 4;          // 6,400,000
  const int nw4 = (CO * 2 * CI) / 4;      // 131,072
  k_convert<<<(nx4 + 255) / 256, 256, 0, stream>>>(x, xb, nx4);
  k_convert<<<(nw4 + 255) / 256, 256, 0, stream>>>(W, Wb, nw4);
  k_degree<<<(E + 255) / 256, 256, 0, stream>>>(dst, cnt, E);
  k_bsum<<<nblk, 256, 0, stream>>>(cnt, bsum, Nn);
  k_scanb<<<1, 256, 0, stream>>>(bsum, boff, nblk);
  k_scanf<<<nblk, 256, 0, stream>>>(cnt, boff, rowptr, Nn);
  k_fill<<<(E + 255) / 256, 256, 0, stream>>>(src, dst, rowptr, cursor, csr, E);
  k_aggregate<<<(Nn + 3) / 4, 256, 0, stream>>>(xb, rowptr, csr, meanb, Nn);

  const int mtiles = (Nn + BM - 1) / BM;  // 391
  k_gemm<<<mtiles * (CO / BN), 256, 0, stream>>>(xb, meanb, Wb, bias, out, Nn);
}